// Round 3
// baseline (363.163 us; speedup 1.0000x reference)
//
#include <hip/hip_runtime.h>

typedef _Float16 f16;
typedef __attribute__((ext_vector_type(8))) _Float16 f16x8;
typedef __attribute__((ext_vector_type(4))) _Float16 f16x4;
typedef __attribute__((ext_vector_type(4))) float    f32x4;

#define B_ROWS 16384
#define MPAD   17408   // 16384 + 8 clusters * 128-row tile padding
#define MTILES 136
#define NBLK   64      // B_ROWS / 256

typedef __attribute__((address_space(1))) void as1_void;
typedef __attribute__((address_space(3))) void as3_void;

__device__ __forceinline__ void gl_lds16(const void* g, void* l) {
    __builtin_amdgcn_global_load_lds((const as1_void*)g, (as3_void*)l, 16, 0, 0);
}

// ---------------- prep: rowmap init + per-block histogram + bias concat + zerobuf ----------------

__global__ __launch_bounds__(256) void k_prep(const int* __restrict__ lbl, int* __restrict__ blockhist,
                                              int* __restrict__ rowmap,
                                              const float* __restrict__ mb_, const float* __restrict__ lb_,
                                              float* __restrict__ bz, f16* __restrict__ zerob) {
    int b = blockIdx.x, t = threadIdx.x;
    int i = b * 256 + t;               // grid = 68 blocks -> MPAD exactly
    rowmap[i] = -1;
    if (b < NBLK) {
        __shared__ int h[8];
        if (t < 8) h[t] = 0;
        __syncthreads();
        atomicAdd(&h[lbl[i]], 1);      // LDS atomic
        __syncthreads();
        if (t < 8) blockhist[b * 8 + t] = h[t];
    } else if (b == NBLK) {
        if (t < 64) zerob[t] = (f16)0.f;       // 128 B of zeros
        if (t < 64) bz[t] = mb_[t];
        else if (t < 128) bz[t] = lb_[t - 64];
    }
}

// single block: cluster totals -> padded offsets, tile->cluster map, per-block bases
__global__ void k_offsets(const int* __restrict__ blockhist, int* offs, int* tilec, int* blockbase) {
    __shared__ int tot[8];
    __shared__ int so[9];
    int t = threadIdx.x;
    if (t < 8) {
        int s = 0;
        for (int b = 0; b < NBLK; ++b) s += blockhist[b * 8 + t];
        tot[t] = s;
    }
    __syncthreads();
    if (t == 0) {
        int o = 0;
        for (int c = 0; c < 8; ++c) { so[c] = o; o += (tot[c] + 127) & ~127; }
        so[8] = o;
        for (int c = 0; c < 9; ++c) offs[c] = so[c];
    }
    __syncthreads();
    if (t < 8) {
        int run = so[t];
        for (int b = 0; b < NBLK; ++b) {
            blockbase[b * 8 + t] = run;
            run += blockhist[b * 8 + t];
        }
    }
    if (t < MTILES) {
        int row = t * 128, c = 7;
        for (int cc = 0; cc < 8; ++cc)
            if (row >= so[cc] && row < so[cc + 1]) c = cc;
        tilec[t] = c;
    }
}

// scatter: LDS cursors seeded from per-block base — zero contended global atomics
__global__ __launch_bounds__(256) void k_scatter(const int* __restrict__ lbl,
                                                 const int* __restrict__ blockbase,
                                                 int* __restrict__ rowmap) {
    __shared__ int cur[8];
    if (threadIdx.x < 8) cur[threadIdx.x] = blockbase[blockIdx.x * 8 + threadIdx.x];
    __syncthreads();
    int i = blockIdx.x * 256 + threadIdx.x;
    int c = lbl[i];
    int pos = atomicAdd(&cur[c], 1);   // LDS atomic
    rowmap[pos] = i;
}

// ---------------- merged convert + 9 weight transposes (one dispatch) ----------------
// seg 0: x fp32 -> xh f16 (flat, 8 elem/thread).
// segs 1..9: [K,N] fp32 -> [N,K] f16, 64x64 tiles, f16x8 vectorized writes.

struct Seg { const float* s; f16* d; int K, N, b0, nx, ny; long sCS, dCS; };
struct SegTab { Seg g[10]; };

__global__ __launch_bounds__(256) void k_trans(SegTab tab, const float* __restrict__ x, f16* __restrict__ xh) {
    int bid = blockIdx.x;
    int t = threadIdx.x;
    if (bid < tab.g[1].b0) {           // cvt segment: 8 f16 per thread
        size_t i = (size_t)bid * 256 + t;
        float4 a = ((const float4*)x)[2 * i];
        float4 b = ((const float4*)x)[2 * i + 1];
        f16x8 o = {(f16)a.x, (f16)a.y, (f16)a.z, (f16)a.w,
                   (f16)b.x, (f16)b.y, (f16)b.z, (f16)b.w};
        ((f16x8*)xh)[i] = o;
        return;
    }
    int s = 9;
    while (bid < tab.g[s].b0) --s;     // block-uniform linear search
    Seg sg = tab.g[s];
    int lb = bid - sg.b0;
    int nxy = sg.nx * sg.ny;
    int z = lb / nxy; int r = lb - z * nxy;
    int by = r / sg.nx; int bx = r - by * sg.nx;
    const float* src = sg.s + (size_t)z * sg.sCS;
    f16* dst = sg.d + (size_t)z * sg.dCS;
    int n0 = bx * 64, k0 = by * 64;
    __shared__ float ld[64][64];
    // read: float4 per thread, 4 passes of 16 rows (coalesced 256B per 16 lanes)
    int cr = t >> 4, cc = (t & 15) * 4;
    #pragma unroll
    for (int i = 0; i < 4; ++i) {
        float4 v = *(const float4*)(src + (size_t)(k0 + cr + 16 * i) * sg.N + n0 + cc);
        *(float4*)&ld[cr + 16 * i][cc] = v;
    }
    __syncthreads();
    // write: f16x8 (16B) per store, lanes sweep n (consecutive output rows -> LDS conflict-free)
    int n = t & 63, gp = t >> 6;
    #pragma unroll
    for (int p = 0; p < 2; ++p) {
        int g = gp + 4 * p;
        f16x8 o;
        #pragma unroll
        for (int j = 0; j < 8; ++j) o[j] = (f16)ld[g * 8 + j][n];
        *(f16x8*)(dst + (size_t)(n0 + n) * sg.K + k0 + g * 8) = o;
    }
}

// ---------------- MFMA GEMM: 128x128 tile, BK=32, XOR-swizzled LDS, XCD-aware 1-D grid ----------
// Depth-1 prefetch pipeline: double-buffered 2x(8K A + 8K B) = 32KB LDS (5 blocks/CU);
// next k-chunk's global_load_lds issued BEFORE current chunk's ds_read+MFMA;
// ONE __syncthreads per k-step (vmcnt(0) drain at end of step = depth-1 wait, loads
// had the whole compute phase in flight).
// A [*, K] f16 (GATHER: rows via rowmap), Wt [C?, N, K] f16, bias [C?, N] fp32.
// EPI 0: Out f16 [MPAD, N], direct stores
// EPI 1: fp32 scatter rows via rowmap to OutF, direct stores
// EPI 2: reparameterize in-kernel: C = [mu|lv] (N=128) staged across full smem, z -> Out [MPAD,64]
// LDS staging layout: [row][granule] 16B granules, 4/row (64B rows); slot s of row r holds
// global granule s ^ ((r>>1)&3).  ((r>>1)&3 — NOT r&3 — needed for bank-evenness: rows repeat
// bank alignment every 2 rows at 64B stride, so the permutation must advance once per row PAIR.)

template<int GATHER, int PERW, int RELU, int EPI>
__global__ __launch_bounds__(256) void gemm_k(
    const f16* __restrict__ A, const f16* __restrict__ Wt,
    const float* __restrict__ bias, f16* __restrict__ Out, float* __restrict__ OutF,
    const float* __restrict__ eps,
    const int* __restrict__ rowmap, const int* __restrict__ tilec,
    const f16* __restrict__ zerobuf, int K, int N)
{
    __shared__ __align__(16) char smem[32768];   // 2 x (lA 8KB + lB 8KB)
    const int tid  = threadIdx.x;
    const int wave = tid >> 6;
    const int lane = tid & 63;

    // XCD-aware swizzle: blocks sharing an A row-tile (same tm) land on the same XCD (id mod 8)
    const int id  = blockIdx.x;
    const int xcd = id & 7;
    const int jj  = id >> 3;
    const int tm  = (jj % 17) * 8 + xcd;   // 0..135
    const int tn  = jj / 17;
    const int r0 = tm * 128, n0 = tn * 128;

    const f16* wb = Wt;
    const float* bb = bias;
    if (PERW) {
        int c = tilec[tm];
        wb += (size_t)c * K * N;
        bb += (size_t)c * N;
    }

    // staging: thread t handles rows (t>>2) and (t>>2)+64; slot sg=t&3 per row;
    // loads global granule sg ^ ((row>>1)&3).  (row>>1)&3 identical for both passes (64 even).
    const int srow = tid >> 2;             // 0..63
    const int sg   = tid & 3;
    const int xk16 = (sg ^ ((srow >> 1) & 3)) * 16;
    const size_t rowB = (size_t)K * 2;     // bytes per row

    const char* pa[2]; size_t stepA[2];
    #pragma unroll
    for (int p = 0; p < 2; ++p) {
        int gr = r0 + p * 64 + srow;
        if (GATHER) {
            int g = rowmap[gr];
            if (g >= 0) { pa[p] = (const char*)(A + (size_t)g * K) + xk16; stepA[p] = 64; }
            else        { pa[p] = (const char*)zerobuf;                    stepA[p] = 0;  }
        } else {
            pa[p] = (const char*)(A + (size_t)gr * K) + xk16; stepA[p] = 64;
        }
    }
    const char* pb = (const char*)(wb + (size_t)(n0 + srow) * K) + xk16;
    const size_t pbOff = 64 * rowB;

    const int mb = (wave >> 1) * 64;
    const int nb = (wave & 1) * 64;
    const int quad = lane >> 4;
    const int r16  = lane & 15;
    const int off  = (quad ^ ((r16 >> 1) & 3)) * 16;   // k-granule quad at its swizzled slot

    // bias load hoisted: independent, hides under the k-loop
    float bv[4];
    #pragma unroll
    for (int j = 0; j < 4; ++j) bv[j] = bb[n0 + nb + j * 16 + r16];

    f32x4 acc[4][4];
    #pragma unroll
    for (int i = 0; i < 4; ++i)
        #pragma unroll
        for (int j = 0; j < 4; ++j)
            acc[i][j] = (f32x4){0.f, 0.f, 0.f, 0.f};

    auto stage = [&](char* dst) {
        gl_lds16(pa[0], dst        + wave * 1024);
        gl_lds16(pa[1], dst + 4096 + wave * 1024);
        gl_lds16(pb,           dst + 8192  + wave * 1024);
        gl_lds16(pb + pbOff,   dst + 12288 + wave * 1024);
        pa[0] += stepA[0]; pa[1] += stepA[1];
        pb += 64;
    };

    auto compute = [&](const char* base) {
        const char* lA = base;
        const char* lB = base + 8192;
        f16x8 af[4], bf[4];
        #pragma unroll
        for (int i = 0; i < 4; ++i)
            af[i] = *(const f16x8*)(lA + (mb + i * 16 + r16) * 64 + off);
        #pragma unroll
        for (int j = 0; j < 4; ++j)
            bf[j] = *(const f16x8*)(lB + (nb + j * 16 + r16) * 64 + off);
        #pragma unroll
        for (int i = 0; i < 4; ++i)
            #pragma unroll
            for (int j = 0; j < 4; ++j)
                acc[i][j] = __builtin_amdgcn_mfma_f32_16x16x32_f16(af[i], bf[j], acc[i][j], 0, 0, 0);
    };

    const int nk = K >> 5;
    // prologue: stage chunk 0 into buffer 0
    stage(smem);
    __syncthreads();                       // vmcnt(0) drain + barrier
    int cur = 0;
    for (int kb = 0; kb < nk - 1; ++kb) {
        stage(smem + ((cur ^ 1) << 14));   // issue next-chunk loads FIRST (overlap with compute)
        compute(smem + (cur << 14));
        __syncthreads();                   // drains prefetch (depth-1 wait) + barrier
        cur ^= 1;
    }
    compute(smem + (cur << 14));           // last chunk, no prefetch

    if (EPI == 2) {
        // stage [mu|lv] f16 C tile across the full smem (128x128x2B = 32KB), then reparam.
        __syncthreads();                   // all waves done reading k-loop LDS
        #pragma unroll
        for (int i = 0; i < 4; ++i) {
            #pragma unroll
            for (int r = 0; r < 4; ++r) {
                int lr = mb + i * 16 + quad * 4 + r;
                #pragma unroll
                for (int j = 0; j < 4; ++j) {
                    int lc = nb + j * 16 + r16;
                    float v = acc[i][j][r] + bv[j];
                    *(f16*)(smem + lr * 256 + ((((lc >> 3) ^ (lr & 7))) << 4) + ((lc & 7) << 1)) = (f16)v;
                }
            }
        }
        __syncthreads();
        const int col = tid & 63;
        const int rb  = tid >> 6;
        for (int rr = 0; rr < 32; ++rr) {
            int row = rb * 32 + rr;              // wave-uniform
            int g = rowmap[r0 + row];            // uniform -> scalar load
            float e = (g >= 0) ? eps[(size_t)g * 64 + col] : 0.f;
            float mu = (float)*(const f16*)(smem + row * 256 + ((((col >> 3) ^ (row & 7))) << 4) + ((col & 7) << 1));
            int c2 = col + 64;
            float lv = (float)*(const f16*)(smem + row * 256 + ((((c2 >> 3) ^ (row & 7))) << 4) + ((c2 & 7) << 1));
            Out[(size_t)(r0 + row) * 64 + col] = (f16)(mu + expf(0.5f * lv) * e);
        }
        return;
    }

    // EPI 0 / 1: direct stores (round-0 proven; L2 write-combines the 32B segments)
    #pragma unroll
    for (int i = 0; i < 4; ++i) {
        #pragma unroll
        for (int r = 0; r < 4; ++r) {
            int orow = r0 + mb + i * 16 + quad * 4 + r;
            int g = 0;
            if (EPI == 1) g = rowmap[orow];
            #pragma unroll
            for (int j = 0; j < 4; ++j) {
                int ocol = n0 + nb + j * 16 + r16;
                float v = acc[i][j][r] + bv[j];
                if (RELU) v = fmaxf(v, 0.f);
                if (EPI == 1) {
                    if (g >= 0) OutF[(size_t)g * N + ocol] = v;
                } else {
                    Out[(size_t)orow * N + ocol] = (f16)v;
                }
            }
        }
    }
}

// ---------------- launch ----------------

extern "C" void kernel_launch(void* const* d_in, const int* in_sizes, int n_in,
                              void* d_out, int out_size, void* d_ws, size_t ws_size,
                              hipStream_t stream) {
    const float* x      = (const float*)d_in[0];
    const int*   lbl    = (const int*)  d_in[1];
    const float* eps    = (const float*)d_in[2];
    const float* enc_W0 = (const float*)d_in[3];
    const float* enc_b0 = (const float*)d_in[4];
    const float* enc_Wu = (const float*)d_in[5];
    const float* enc_bu = (const float*)d_in[6];
    const float* enc_W2 = (const float*)d_in[7];
    const float* enc_b2 = (const float*)d_in[8];
    const float* mu_W   = (const float*)d_in[9];
    const float* mu_b   = (const float*)d_in[10];
    const float* lv_W   = (const float*)d_in[11];
    const float* lv_b   = (const float*)d_in[12];
    const float* dWu0   = (const float*)d_in[13];
    const float* dbu0   = (const float*)d_in[14];
    const float* dW1    = (const float*)d_in[15];
    const float* db1    = (const float*)d_in[16];
    const float* dWu2   = (const float*)d_in[17];
    const float* dbu2   = (const float*)d_in[18];
    const float* finW   = (const float*)d_in[19];
    const float* finb   = (const float*)d_in[20];
    float* out = (float*)d_out;
    (void)in_sizes; (void)n_in; (void)out_size; (void)ws_size;

    char* base = (char*)d_ws;
    size_t off = 0;
    auto alloc = [&](size_t bytes) { char* r = base + off; off = (off + bytes + 255) & ~(size_t)255; return r; };
    f16* xh     = (f16*)alloc((size_t)B_ROWS * 512 * 2);
    f16* buf1   = (f16*)alloc((size_t)MPAD * 1024 * 2);  // h1 / h6
    f16* buf2   = (f16*)alloc((size_t)MPAD * 512 * 2);   // h2 / h5
    f16* buf3   = (f16*)alloc((size_t)MPAD * 256 * 2);   // h3 / h4
    f16* zb     = (f16*)alloc((size_t)MPAD * 64 * 2);
    f16* w0t    = (f16*)alloc(1024ul * 512 * 2);
    f16* wut    = (f16*)alloc(8ul * 512 * 1024 * 2);
    f16* w2t    = (f16*)alloc(256ul * 512 * 2);
    f16* wzt    = (f16*)alloc(128ul * 256 * 2);
    f16* wd0t   = (f16*)alloc(8ul * 256 * 64 * 2);
    f16* wd1t   = (f16*)alloc(512ul * 256 * 2);
    f16* wd2t   = (f16*)alloc(8ul * 1024 * 512 * 2);
    f16* wft    = (f16*)alloc(8ul * 512 * 1024 * 2);
    float* bz   = (float*)alloc(128 * 4);
    int* rowmap = (int*)alloc(MPAD * 4);
    int* blockhist = (int*)alloc(NBLK * 8 * 4);
    int* blockbase = (int*)alloc(NBLK * 8 * 4);
    int* offs   = (int*)alloc(64);
    int* tilec  = (int*)alloc(MTILES * 4);
    f16* zerob  = (f16*)alloc(256);

    // cluster sort + bias concat
    k_prep<<<MPAD / 256, 256, 0, stream>>>(lbl, blockhist, rowmap, mu_b, lv_b, bz, zerob);
    k_offsets<<<1, 256, 0, stream>>>(blockhist, offs, tilec, blockbase);
    k_scatter<<<NBLK, 256, 0, stream>>>(lbl, blockbase, rowmap);

    // merged convert + transposes: seg0 cvt (4096 blocks, 8/thread), segs 1..9 transposes (64x64)
    SegTab tab;
    int b0 = B_ROWS * 512 / 8 / 256;   // 4096
    auto seg = [&](int i, const float* s, f16* d, int K, int N, int nz, long sCS, long dCS) {
        int nx = N / 64, ny = K / 64;
        tab.g[i] = Seg{s, d, K, N, b0, nx, ny, sCS, dCS};
        b0 += nx * ny * nz;
    };
    tab.g[0] = Seg{nullptr, nullptr, 0, 0, 0, 0, 0, 0, 0};
    seg(1, enc_W0, w0t, 512, 1024, 1, 0, 0);
    seg(2, enc_Wu, wut, 1024, 512, 8, 1024l * 512, 512l * 1024);
    seg(3, enc_W2, w2t, 512, 256, 1, 0, 0);
    seg(4, mu_W, wzt, 256, 64, 1, 0, 0);
    seg(5, lv_W, wzt + 64 * 256, 256, 64, 1, 0, 0);
    seg(6, dWu0, wd0t, 64, 256, 8, 64l * 256, 256l * 64);
    seg(7, dW1, wd1t, 256, 512, 1, 0, 0);
    seg(8, dWu2, wd2t, 512, 1024, 8, 512l * 1024, 1024l * 512);
    seg(9, finW, wft, 1024, 512, 8, 1024l * 512, 512l * 1024);
    k_trans<<<b0, 256, 0, stream>>>(tab, x, xh);

    // encoder
    gemm_k<1,0,1,0><<<MTILES * 8, 256, 0, stream>>>(xh,   w0t,  enc_b0, buf1, nullptr, nullptr, rowmap, tilec, zerob, 512, 1024);
    gemm_k<0,1,1,0><<<MTILES * 4, 256, 0, stream>>>(buf1, wut,  enc_bu, buf2, nullptr, nullptr, rowmap, tilec, zerob, 1024, 512);
    gemm_k<0,0,1,0><<<MTILES * 2, 256, 0, stream>>>(buf2, w2t,  enc_b2, buf3, nullptr, nullptr, rowmap, tilec, zerob, 512, 256);
    // latent heads (mu|logvar fused, no relu) + in-kernel reparameterize -> z
    gemm_k<0,0,0,2><<<MTILES * 1, 256, 0, stream>>>(buf3, wzt,  bz,     zb,   nullptr, eps,     rowmap, tilec, zerob, 256, 128);
    // decoder
    gemm_k<0,1,1,0><<<MTILES * 2, 256, 0, stream>>>(zb,   wd0t, dbu0,   buf3, nullptr, nullptr, rowmap, tilec, zerob, 64, 256);
    gemm_k<0,0,1,0><<<MTILES * 4, 256, 0, stream>>>(buf3, wd1t, db1,    buf2, nullptr, nullptr, rowmap, tilec, zerob, 256, 512);
    gemm_k<0,1,1,0><<<MTILES * 8, 256, 0, stream>>>(buf2, wd2t, dbu2,   buf1, nullptr, nullptr, rowmap, tilec, zerob, 512, 1024);
    // final per-cluster layer, fp32 scatter to d_out
    gemm_k<0,1,0,1><<<MTILES * 4, 256, 0, stream>>>(buf1, wft,  finb,   nullptr, out,  nullptr, rowmap, tilec, zerob, 1024, 512);
}

// Round 4
// 361.424 us; speedup vs baseline: 1.0048x; 1.0048x over previous
//
#include <hip/hip_runtime.h>

typedef _Float16 f16;
typedef __attribute__((ext_vector_type(8))) _Float16 f16x8;
typedef __attribute__((ext_vector_type(4))) _Float16 f16x4;
typedef __attribute__((ext_vector_type(4))) float    f32x4;

#define B_ROWS 16384
#define MPAD   17408   // 16384 + 8 clusters * 128-row tile padding
#define MTILES 136
#define NBLK   64      // B_ROWS / 256

typedef __attribute__((address_space(1))) void as1_void;
typedef __attribute__((address_space(3))) void as3_void;

__device__ __forceinline__ void gl_lds16(const void* g, void* l) {
    __builtin_amdgcn_global_load_lds((const as1_void*)g, (as3_void*)l, 16, 0, 0);
}

// ---------------- prep: rowmap init + per-block histogram + bias concat + zerobuf ----------------

__global__ __launch_bounds__(256) void k_prep(const int* __restrict__ lbl, int* __restrict__ blockhist,
                                              int* __restrict__ rowmap,
                                              const float* __restrict__ mb_, const float* __restrict__ lb_,
                                              float* __restrict__ bz, f16* __restrict__ zerob) {
    int b = blockIdx.x, t = threadIdx.x;
    int i = b * 256 + t;               // grid = 68 blocks -> MPAD exactly
    rowmap[i] = -1;
    if (b < NBLK) {
        __shared__ int h[8];
        if (t < 8) h[t] = 0;
        __syncthreads();
        atomicAdd(&h[lbl[i]], 1);      // LDS atomic
        __syncthreads();
        if (t < 8) blockhist[b * 8 + t] = h[t];
    } else if (b == NBLK) {
        if (t < 64) zerob[t] = (f16)0.f;       // 128 B of zeros
        if (t < 64) bz[t] = mb_[t];
        else if (t < 128) bz[t] = lb_[t - 64];
    }
}

// single block: cluster totals -> padded offsets, tile->cluster map, per-block bases
__global__ void k_offsets(const int* __restrict__ blockhist, int* offs, int* tilec, int* blockbase) {
    __shared__ int tot[8];
    __shared__ int so[9];
    int t = threadIdx.x;
    if (t < 8) {
        int s = 0;
        for (int b = 0; b < NBLK; ++b) s += blockhist[b * 8 + t];
        tot[t] = s;
    }
    __syncthreads();
    if (t == 0) {
        int o = 0;
        for (int c = 0; c < 8; ++c) { so[c] = o; o += (tot[c] + 127) & ~127; }
        so[8] = o;
        for (int c = 0; c < 9; ++c) offs[c] = so[c];
    }
    __syncthreads();
    if (t < 8) {
        int run = so[t];
        for (int b = 0; b < NBLK; ++b) {
            blockbase[b * 8 + t] = run;
            run += blockhist[b * 8 + t];
        }
    }
    if (t < MTILES) {
        int row = t * 128, c = 7;
        for (int cc = 0; cc < 8; ++cc)
            if (row >= so[cc] && row < so[cc + 1]) c = cc;
        tilec[t] = c;
    }
}

// scatter: LDS cursors seeded from per-block base — zero contended global atomics
__global__ __launch_bounds__(256) void k_scatter(const int* __restrict__ lbl,
                                                 const int* __restrict__ blockbase,
                                                 int* __restrict__ rowmap) {
    __shared__ int cur[8];
    if (threadIdx.x < 8) cur[threadIdx.x] = blockbase[blockIdx.x * 8 + threadIdx.x];
    __syncthreads();
    int i = blockIdx.x * 256 + threadIdx.x;
    int c = lbl[i];
    int pos = atomicAdd(&cur[c], 1);   // LDS atomic
    rowmap[pos] = i;
}

// ---------------- merged convert + 9 weight transposes (one dispatch) ----------------
// seg 0: x fp32 -> xh f16 (flat, 8 elem/thread).
// segs 1..9: [K,N] fp32 -> [N,K] f16, 64x64 tiles.
// Write phase emits FULL 128-B segments per wave-store: lane>>3 = output row in an
// 8-row group, lane&7 = 16B k-granule  ->  8 x 128B contiguous segments per instruction
// (vs 64 x 16B partial lines before: WRITE_SIZE showed 1.56x RMW amplification).
// LDS tile uses a 16B-granule XOR swizzle: col granule (c>>2) stored at (c>>2)^(r&15),
// keeping float4 alignment; write phase conflict-free, read phase <=4-way on scalars.

struct Seg { const float* s; f16* d; int K, N, b0, nx, ny; long sCS, dCS; };
struct SegTab { Seg g[10]; };

__global__ __launch_bounds__(256) void k_trans(SegTab tab, const float* __restrict__ x, f16* __restrict__ xh) {
    int bid = blockIdx.x;
    int t = threadIdx.x;
    if (bid < tab.g[1].b0) {           // cvt segment: 8 f16 per thread
        size_t i = (size_t)bid * 256 + t;
        float4 a = ((const float4*)x)[2 * i];
        float4 b = ((const float4*)x)[2 * i + 1];
        f16x8 o = {(f16)a.x, (f16)a.y, (f16)a.z, (f16)a.w,
                   (f16)b.x, (f16)b.y, (f16)b.z, (f16)b.w};
        ((f16x8*)xh)[i] = o;
        return;
    }
    int s = 9;
    while (bid < tab.g[s].b0) --s;     // block-uniform linear search
    Seg sg = tab.g[s];
    int lb = bid - sg.b0;
    int nxy = sg.nx * sg.ny;
    int z = lb / nxy; int r = lb - z * nxy;
    int by = r / sg.nx; int bx = r - by * sg.nx;
    const float* src = sg.s + (size_t)z * sg.sCS;
    f16* dst = sg.d + (size_t)z * sg.dCS;
    int n0 = bx * 64, k0 = by * 64;
    __shared__ float ld[64][64];
    // read: float4 per thread, 4 passes of 16 rows (coalesced 256B per 16 lanes), swizzled store
    int cr = t >> 4, cc = (t & 15) * 4;
    #pragma unroll
    for (int i = 0; i < 4; ++i) {
        int rr = cr + 16 * i;
        float4 v = *(const float4*)(src + (size_t)(k0 + rr) * sg.N + n0 + cc);
        *(float4*)&ld[rr][(((cc >> 2) ^ (rr & 15)) << 2)] = v;
    }
    __syncthreads();
    // write: granule G = p*256 + t; n = G>>3 (out row), gg = G&7 (16B k-granule)
    #pragma unroll
    for (int p = 0; p < 2; ++p) {
        int G = p * 256 + t;
        int n = G >> 3, gg = G & 7;
        f16x8 o;
        #pragma unroll
        for (int j = 0; j < 8; ++j) {
            int kk = gg * 8 + j;
            o[j] = (f16)ld[kk][(((n >> 2) ^ (kk & 15)) << 2) | (n & 3)];
        }
        *(f16x8*)(dst + (size_t)(n0 + n) * sg.K + k0 + gg * 8) = o;
    }
}

// ---------------- MFMA GEMM: 128x128 tile, BK=64, XOR-swizzled LDS, XCD-aware 1-D grid ----------
// COUNTED-VMCNT double-buffer (T4): raw s_barrier + asm vmcnt(8) -- prefetched loads stay in
// flight ACROSS barriers (vs __syncthreads' forced vmcnt(0) drain, which made rounds 2-3 neutral).
// Per k-step: stage(next buf) [8 global_load_lds] ; vmcnt(8) waits only the PREVIOUS stage's 8;
// barrier (collective: every wave's cur-buffer loads landed); compute; barrier (protects reuse).
// Bias loads are issued BEFORE the prologue stage so the first vmcnt(8) drains them as oldest.
// A [*, K] f16 (GATHER: rows via rowmap), Wt [C?, N, K] f16, bias [C?, N] fp32.
// EPI 0: Out f16 [MPAD, N], direct stores
// EPI 1: fp32 scatter rows via rowmap to OutF, direct stores
// EPI 2: reparameterize in-kernel: C = [mu|lv] (N=128) staged in LDS, z -> Out [MPAD,64]
// LDS staging layout: [row][granule] 16B granules, 8/row; slot g of row r holds global
// granule g ^ (r&7); compute reads slot ((kk*4+quad) ^ (r16&7)) -- conflict-free (round-1-proven).

template<int GATHER, int PERW, int RELU, int EPI>
__global__ __launch_bounds__(256) void gemm_k(
    const f16* __restrict__ A, const f16* __restrict__ Wt,
    const float* __restrict__ bias, f16* __restrict__ Out, float* __restrict__ OutF,
    const float* __restrict__ eps,
    const int* __restrict__ rowmap, const int* __restrict__ tilec,
    const f16* __restrict__ zerobuf, int K, int N)
{
    __shared__ __align__(16) char smem[65536];   // 2 x (lA 16KB + lB 16KB)
    const int tid  = threadIdx.x;
    const int wave = tid >> 6;
    const int lane = tid & 63;

    // XCD-aware swizzle: blocks sharing an A row-tile (same tm) land on the same XCD (id mod 8)
    const int id  = blockIdx.x;
    const int xcd = id & 7;
    const int jj  = id >> 3;
    const int tm  = (jj % 17) * 8 + xcd;   // 0..135
    const int tn  = jj / 17;
    const int r0 = tm * 128, n0 = tn * 128;

    const f16* wb = Wt;
    const float* bb = bias;
    if (PERW) {
        int c = tilec[tm];
        wb += (size_t)c * K * N;
        bb += (size_t)c * N;
    }

    // staging: thread t loads granule (sg ^ (srow&7)) of row (pass*32 + srow) each k-chunk
    const int srow = tid >> 3;             // 0..31
    const int sg   = tid & 7;              // 0..7
    const int xk16 = (sg ^ (srow & 7)) * 16;   // r0,n0 are multiples of 128 -> key = srow&7
    const size_t rowB = (size_t)K * 2;     // bytes per row
    const size_t passB = 32 * rowB;        // bytes per 32-row pass group

    const char* pa[4]; size_t stepA[4];
    #pragma unroll
    for (int p = 0; p < 4; ++p) {
        int gr = r0 + p * 32 + srow;
        if (GATHER) {
            int g = rowmap[gr];            // value needed for address -> drained before staging
            if (g >= 0) { pa[p] = (const char*)(A + (size_t)g * K) + xk16; stepA[p] = 128; }
            else        { pa[p] = (const char*)zerobuf;                    stepA[p] = 0;   }
        } else {
            pa[p] = (const char*)(A + (size_t)gr * K) + xk16; stepA[p] = 128;
        }
    }
    const char* pb = (const char*)(wb + (size_t)(n0 + srow) * K) + xk16;

    const int mb = (wave >> 1) * 64;
    const int nb = (wave & 1) * 64;
    const int quad = lane >> 4;
    const int r16  = lane & 15;
    const int key  = r16 & 7;

    // bias issued BEFORE prologue stage: first vmcnt(8) drains these as the oldest entries
    float bv[4];
    #pragma unroll
    for (int j = 0; j < 4; ++j) bv[j] = bb[n0 + nb + j * 16 + r16];

    f32x4 acc[4][4];
    #pragma unroll
    for (int i = 0; i < 4; ++i)
        #pragma unroll
        for (int j = 0; j < 4; ++j)
            acc[i][j] = (f32x4){0.f, 0.f, 0.f, 0.f};

    auto stage = [&](char* dst) {
        #pragma unroll
        for (int p = 0; p < 4; ++p)
            gl_lds16(pa[p], dst + p * 4096 + wave * 1024);
        #pragma unroll
        for (int p = 0; p < 4; ++p)
            gl_lds16(pb + p * passB, dst + 16384 + p * 4096 + wave * 1024);
        #pragma unroll
        for (int p = 0; p < 4; ++p) pa[p] += stepA[p];
        pb += 128;
    };

    auto compute = [&](const char* base) {
        const char* lA = base;
        const char* lB = base + 16384;
        #pragma unroll
        for (int kk = 0; kk < 2; ++kk) {
            const int off = ((kk * 4 + quad) ^ key) * 16;
            f16x8 af[4], bf[4];
            #pragma unroll
            for (int i = 0; i < 4; ++i)
                af[i] = *(const f16x8*)(lA + (mb + i * 16 + r16) * 128 + off);
            #pragma unroll
            for (int j = 0; j < 4; ++j)
                bf[j] = *(const f16x8*)(lB + (nb + j * 16 + r16) * 128 + off);
            #pragma unroll
            for (int i = 0; i < 4; ++i)
                #pragma unroll
                for (int j = 0; j < 4; ++j)
                    acc[i][j] = __builtin_amdgcn_mfma_f32_16x16x32_f16(af[i], bf[j], acc[i][j], 0, 0, 0);
        }
    };

    const int nk = K >> 6;
    // prologue: stage chunk 0 into buffer 0 (8 loads in flight; no barrier yet)
    stage(smem);
    int cur = 0;
    for (int kb = 0; kb < nk - 1; ++kb) {
        stage(smem + ((cur ^ 1) << 15));                   // +8 loads (next buffer)
        asm volatile("s_waitcnt vmcnt(8)" ::: "memory");   // own cur-buffer loads landed
        __builtin_amdgcn_s_barrier();                      // -> ALL waves' cur loads landed
        compute(smem + (cur << 15));
        __builtin_amdgcn_s_barrier();                      // cur fully read; next iter may overwrite
        cur ^= 1;
    }
    asm volatile("s_waitcnt vmcnt(0)" ::: "memory");
    __builtin_amdgcn_s_barrier();
    compute(smem + (cur << 15));                           // last chunk

    if (EPI == 2) {
        // stage [mu|lv] f16 C tile (128x128x2B = 32KB) in LDS, then reparameterize.
        __syncthreads();                   // all waves done reading k-loop LDS
        #pragma unroll
        for (int i = 0; i < 4; ++i) {
            #pragma unroll
            for (int r = 0; r < 4; ++r) {
                int lr = mb + i * 16 + quad * 4 + r;
                #pragma unroll
                for (int j = 0; j < 4; ++j) {
                    int lc = nb + j * 16 + r16;
                    float v = acc[i][j][r] + bv[j];
                    *(f16*)(smem + lr * 256 + ((((lc >> 3) ^ (lr & 7))) << 4) + ((lc & 7) << 1)) = (f16)v;
                }
            }
        }
        __syncthreads();
        const int col = tid & 63;
        const int rb  = tid >> 6;
        for (int rr = 0; rr < 32; ++rr) {
            int row = rb * 32 + rr;              // wave-uniform
            int g = rowmap[r0 + row];            // uniform -> scalar load
            float e = (g >= 0) ? eps[(size_t)g * 64 + col] : 0.f;
            float mu = (float)*(const f16*)(smem + row * 256 + ((((col >> 3) ^ (row & 7))) << 4) + ((col & 7) << 1));
            int c2 = col + 64;
            float lv = (float)*(const f16*)(smem + row * 256 + ((((c2 >> 3) ^ (row & 7))) << 4) + ((c2 & 7) << 1));
            Out[(size_t)(r0 + row) * 64 + col] = (f16)(mu + expf(0.5f * lv) * e);
        }
        return;
    }

    // EPI 0 / 1: direct stores (round-0 proven; L2 write-combines the 32B segments)
    #pragma unroll
    for (int i = 0; i < 4; ++i) {
        #pragma unroll
        for (int r = 0; r < 4; ++r) {
            int orow = r0 + mb + i * 16 + quad * 4 + r;
            int g = 0;
            if (EPI == 1) g = rowmap[orow];
            #pragma unroll
            for (int j = 0; j < 4; ++j) {
                int ocol = n0 + nb + j * 16 + r16;
                float v = acc[i][j][r] + bv[j];
                if (RELU) v = fmaxf(v, 0.f);
                if (EPI == 1) {
                    if (g >= 0) OutF[(size_t)g * N + ocol] = v;
                } else {
                    Out[(size_t)orow * N + ocol] = (f16)v;
                }
            }
        }
    }
}

// ---------------- launch ----------------

extern "C" void kernel_launch(void* const* d_in, const int* in_sizes, int n_in,
                              void* d_out, int out_size, void* d_ws, size_t ws_size,
                              hipStream_t stream) {
    const float* x      = (const float*)d_in[0];
    const int*   lbl    = (const int*)  d_in[1];
    const float* eps    = (const float*)d_in[2];
    const float* enc_W0 = (const float*)d_in[3];
    const float* enc_b0 = (const float*)d_in[4];
    const float* enc_Wu = (const float*)d_in[5];
    const float* enc_bu = (const float*)d_in[6];
    const float* enc_W2 = (const float*)d_in[7];
    const float* enc_b2 = (const float*)d_in[8];
    const float* mu_W   = (const float*)d_in[9];
    const float* mu_b   = (const float*)d_in[10];
    const float* lv_W   = (const float*)d_in[11];
    const float* lv_b   = (const float*)d_in[12];
    const float* dWu0   = (const float*)d_in[13];
    const float* dbu0   = (const float*)d_in[14];
    const float* dW1    = (const float*)d_in[15];
    const float* db1    = (const float*)d_in[16];
    const float* dWu2   = (const float*)d_in[17];
    const float* dbu2   = (const float*)d_in[18];
    const float* finW   = (const float*)d_in[19];
    const float* finb   = (const float*)d_in[20];
    float* out = (float*)d_out;
    (void)in_sizes; (void)n_in; (void)out_size; (void)ws_size;

    char* base = (char*)d_ws;
    size_t off = 0;
    auto alloc = [&](size_t bytes) { char* r = base + off; off = (off + bytes + 255) & ~(size_t)255; return r; };
    f16* xh     = (f16*)alloc((size_t)B_ROWS * 512 * 2);
    f16* buf1   = (f16*)alloc((size_t)MPAD * 1024 * 2);  // h1 / h6
    f16* buf2   = (f16*)alloc((size_t)MPAD * 512 * 2);   // h2 / h5
    f16* buf3   = (f16*)alloc((size_t)MPAD * 256 * 2);   // h3 / h4
    f16* zb     = (f16*)alloc((size_t)MPAD * 64 * 2);
    f16* w0t    = (f16*)alloc(1024ul * 512 * 2);
    f16* wut    = (f16*)alloc(8ul * 512 * 1024 * 2);
    f16* w2t    = (f16*)alloc(256ul * 512 * 2);
    f16* wzt    = (f16*)alloc(128ul * 256 * 2);
    f16* wd0t   = (f16*)alloc(8ul * 256 * 64 * 2);
    f16* wd1t   = (f16*)alloc(512ul * 256 * 2);
    f16* wd2t   = (f16*)alloc(8ul * 1024 * 512 * 2);
    f16* wft    = (f16*)alloc(8ul * 512 * 1024 * 2);
    float* bz   = (float*)alloc(128 * 4);
    int* rowmap = (int*)alloc(MPAD * 4);
    int* blockhist = (int*)alloc(NBLK * 8 * 4);
    int* blockbase = (int*)alloc(NBLK * 8 * 4);
    int* offs   = (int*)alloc(64);
    int* tilec  = (int*)alloc(MTILES * 4);
    f16* zerob  = (f16*)alloc(256);

    // cluster sort + bias concat
    k_prep<<<MPAD / 256, 256, 0, stream>>>(lbl, blockhist, rowmap, mu_b, lv_b, bz, zerob);
    k_offsets<<<1, 256, 0, stream>>>(blockhist, offs, tilec, blockbase);
    k_scatter<<<NBLK, 256, 0, stream>>>(lbl, blockbase, rowmap);

    // merged convert + transposes: seg0 cvt (4096 blocks, 8/thread), segs 1..9 transposes (64x64)
    SegTab tab;
    int b0 = B_ROWS * 512 / 8 / 256;   // 4096
    auto seg = [&](int i, const float* s, f16* d, int K, int N, int nz, long sCS, long dCS) {
        int nx = N / 64, ny = K / 64;
        tab.g[i] = Seg{s, d, K, N, b0, nx, ny, sCS, dCS};
        b0 += nx * ny * nz;
    };
    tab.g[0] = Seg{nullptr, nullptr, 0, 0, 0, 0, 0, 0, 0};
    seg(1, enc_W0, w0t, 512, 1024, 1, 0, 0);
    seg(2, enc_Wu, wut, 1024, 512, 8, 1024l * 512, 512l * 1024);
    seg(3, enc_W2, w2t, 512, 256, 1, 0, 0);
    seg(4, mu_W, wzt, 256, 64, 1, 0, 0);
    seg(5, lv_W, wzt + 64 * 256, 256, 64, 1, 0, 0);
    seg(6, dWu0, wd0t, 64, 256, 8, 64l * 256, 256l * 64);
    seg(7, dW1, wd1t, 256, 512, 1, 0, 0);
    seg(8, dWu2, wd2t, 512, 1024, 8, 512l * 1024, 1024l * 512);
    seg(9, finW, wft, 1024, 512, 8, 1024l * 512, 512l * 1024);
    k_trans<<<b0, 256, 0, stream>>>(tab, x, xh);

    // encoder
    gemm_k<1,0,1,0><<<MTILES * 8, 256, 0, stream>>>(xh,   w0t,  enc_b0, buf1, nullptr, nullptr, rowmap, tilec, zerob, 512, 1024);
    gemm_k<0,1,1,0><<<MTILES * 4, 256, 0, stream>>>(buf1, wut,  enc_bu, buf2, nullptr, nullptr, rowmap, tilec, zerob, 1024, 512);
    gemm_k<0,0,1,0><<<MTILES * 2, 256, 0, stream>>>(buf2, w2t,  enc_b2, buf3, nullptr, nullptr, rowmap, tilec, zerob, 512, 256);
    // latent heads (mu|logvar fused, no relu) + in-kernel reparameterize -> z
    gemm_k<0,0,0,2><<<MTILES * 1, 256, 0, stream>>>(buf3, wzt,  bz,     zb,   nullptr, eps,     rowmap, tilec, zerob, 256, 128);
    // decoder
    gemm_k<0,1,1,0><<<MTILES * 2, 256, 0, stream>>>(zb,   wd0t, dbu0,   buf3, nullptr, nullptr, rowmap, tilec, zerob, 64, 256);
    gemm_k<0,0,1,0><<<MTILES * 4, 256, 0, stream>>>(buf3, wd1t, db1,    buf2, nullptr, nullptr, rowmap, tilec, zerob, 256, 512);
    gemm_k<0,1,1,0><<<MTILES * 8, 256, 0, stream>>>(buf2, wd2t, dbu2,   buf1, nullptr, nullptr, rowmap, tilec, zerob, 512, 1024);
    // final per-cluster layer, fp32 scatter to d_out
    gemm_k<0,1,0,1><<<MTILES * 4, 256, 0, stream>>>(buf1, wft,  finb,   nullptr, out,  nullptr, rowmap, tilec, zerob, 1024, 512);
}